// Round 3
// baseline (224.525 us; speedup 1.0000x reference)
//
#include <hip/hip_runtime.h>
#include <hip/hip_bf16.h>
#include <math.h>

// Problem constants
constexpr int B    = 256;
constexpr int S    = 512;
constexpr int E    = 256;
constexpr int PD   = 32;
constexpr int FEAT = 320;   // E + 2*PD
constexpr int FN   = 230;
constexpr int FNP  = 256;   // padded filter count
constexpr int TAG  = 53;
constexpr int K    = 960;   // 3 * FEAT
constexpr int BM   = 128;   // s-rows per block
constexpr int KS   = 32;    // K per MFMA step
constexpr int NG   = 10;    // feature groups (320/32)
constexpr int LDA  = 36;    // LDS row stride (bf16): 72 B -> bank stride 18, gcd(18,32)=2 (free)
constexpr int LDB  = 36;

typedef short  bf16x8 __attribute__((ext_vector_type(8)));  // 8 bf16 in 4 VGPRs
typedef float  f32x4  __attribute__((ext_vector_type(4)));

__device__ __forceinline__ unsigned f2bf(float x) {
    union { float f; unsigned u; } v; v.f = x;
    unsigned r = v.u + 0x7FFF + ((v.u >> 16) & 1);   // RNE (finite inputs)
    return r >> 16;
}
__device__ __forceinline__ unsigned pack2(float a, float b) {
    return f2bf(a) | (f2bf(b) << 16);
}

// ---------------------------------------------------------------------------
// Kernel 0: transpose + convert conv_w [K=960][FN=230] -> wt[n][k] bf16,
// n padded to FNP=256 with zeros. LDS-tiled so both sides are coalesced.
// grid = (K/32, FNP/32), block = 256 (tx = 0..31, ty = 0..7)
// ---------------------------------------------------------------------------
__global__ __launch_bounds__(256) void wt_prep_kernel(
    const float* __restrict__ conv_w, unsigned short* __restrict__ wt)
{
    __shared__ float tile[32][33];
    const int tx = threadIdx.x & 31;
    const int ty = threadIdx.x >> 5;
    const int k0 = blockIdx.x * 32;
    const int n0 = blockIdx.y * 32;
#pragma unroll
    for (int i = 0; i < 4; ++i) {
        int k = k0 + ty + i * 8;
        int n = n0 + tx;
        tile[ty + i * 8][tx] = (n < FN) ? conv_w[(size_t)k * FN + n] : 0.0f;
    }
    __syncthreads();
#pragma unroll
    for (int i = 0; i < 4; ++i) {
        int n = n0 + ty + i * 8;
        int k = k0 + tx;
        wt[(size_t)n * K + k] = (unsigned short)f2bf(tile[tx][ty + i * 8]);
    }
}

// ---------------------------------------------------------------------------
// Kernel A: per-batch entity bounds + zero pcnn workspace
// segb[b] = {a_end, b_start, b_end, c_start}
// ---------------------------------------------------------------------------
__global__ __launch_bounds__(256) void bounds_kernel(
    const int* __restrict__ pos1, const int* __restrict__ pos2,
    int* __restrict__ segb, unsigned* __restrict__ pcnn)
{
    const int b = blockIdx.x;
    const int tid = threadIdx.x;
    __shared__ int r[4]; // p1min, p1max, p2min, p2max
    if (tid == 0) { r[0] = S; r[1] = -1; r[2] = S; r[3] = -1; }
    __syncthreads();
    for (int s = tid; s < S; s += 256) {
        if (pos1[b * S + s] == 60) { atomicMin(&r[0], s); atomicMax(&r[1], s); }
        if (pos2[b * S + s] == 60) { atomicMin(&r[2], s); atomicMax(&r[3], s); }
    }
    __syncthreads();
    if (tid == 0) {
        int p1min = r[0], p1max = r[1], p2min = r[2], p2max = r[3];
        bool first = p1min < p2min;
        int m1 = first ? p1min : p2min;
        int m2 = first ? p1max : p2max;
        int m3 = first ? p2min : p1min;
        int m4 = first ? p2max : p1max;
        int4 o;
        o.x = max(m1, 1);       // mask_a: s <  a_end
        o.y = m2;               // mask_b: s >= b_start
        o.z = max(m3, m2 + 1);  // mask_b: s <  b_end
        o.w = m4;               // mask_c: s >= c_start
        *(int4*)(segb + b * 4) = o;
    }
    unsigned* pc = pcnn + (size_t)b * 3 * FNP;
    for (int i = tid; i < 3 * FNP; i += 256) pc[i] = 0u;
}

// ---------------------------------------------------------------------------
// Kernel B: fused embed-gather + conv1d(win=3,pad=1) via bf16 MFMA
//           + bias + ReLU + segment-max
// grid = (S/BM, B); block = 512 threads = 8 waves (2 M x 4 N), wave tile 64x64
// Outer loop: 10 feature groups (A staged ONCE per group);
// inner loop: 3 conv windows (B slice restaged; A frags read at row offset +w)
// ---------------------------------------------------------------------------
__global__ __launch_bounds__(512, 4) void conv_mfma_kernel(
    const int* __restrict__ sentence, const int* __restrict__ pos1,
    const int* __restrict__ pos2,
    const float* __restrict__ word_emb, const float* __restrict__ pos1_emb,
    const float* __restrict__ pos2_emb,
    const unsigned short* __restrict__ wt, const float* __restrict__ conv_b,
    const int* __restrict__ segb, unsigned* __restrict__ pcnn)
{
    __shared__ __align__(16) unsigned short ldsA[(BM + 2) * LDA]; //  9360 B
    __shared__ __align__(16) unsigned short ldsB[FNP * LDB];      // 18432 B
    __shared__ unsigned maxbuf[3 * FNP];                          //  3072 B

    const int tid  = threadIdx.x;
    const int b    = blockIdx.y;
    const int s0   = blockIdx.x * BM;
    const int lane = tid & 63;
    const int wid  = tid >> 6;
    const int wm   = wid >> 2;      // 0..1  (M band of 64)
    const int wn   = wid & 3;       // 0..3  (N band of 64)
    const int lrow = lane & 15;
    const int lgrp = lane >> 4;

    for (int i = tid; i < 3 * FNP; i += 512) maxbuf[i] = 0u;

    const int* sent_b = sentence + b * S;
    const int* p1_b   = pos1 + b * S;
    const int* p2_b   = pos2 + b * S;

    f32x4 acc[4][4];
#pragma unroll
    for (int i = 0; i < 4; ++i)
#pragma unroll
        for (int j = 0; j < 4; ++j) acc[i][j] = (f32x4){0.f, 0.f, 0.f, 0.f};

    for (int g = 0; g < NG; ++g) {
        const int fb = g * KS;          // feature base 0..288

        __syncthreads();   // all waves done reading previous A and B tiles

        // ---- stage A: 130 rows x 32 feats (gather + f32->bf16), once/group
        {
            int c = tid;
#pragma unroll
            for (int rep = 0; rep < 2; ++rep, c += 512) {
                if (c < (BM + 2) * 4) {
                    int r = c >> 2, q = c & 3;
                    int s = s0 - 1 + r;
                    int feat = fb + q * 8;
                    float4 v0 = make_float4(0.f, 0.f, 0.f, 0.f);
                    float4 v1 = v0;
                    if (s >= 0 && s < S) {
                        const float* p;
                        if (feat < E)            p = word_emb + (size_t)sent_b[s] * E + feat;
                        else if (feat < E + PD)  p = pos1_emb + p1_b[s] * PD + (feat - E);
                        else                     p = pos2_emb + p2_b[s] * PD + (feat - E - PD);
                        v0 = *(const float4*)p;
                        v1 = *(const float4*)(p + 4);
                    }
                    uint4 pk;
                    pk.x = pack2(v0.x, v0.y);
                    pk.y = pack2(v0.z, v0.w);
                    pk.z = pack2(v1.x, v1.y);
                    pk.w = pack2(v1.z, v1.w);
                    *(uint4*)&ldsA[r * LDA + q * 8] = pk;
                }
            }
        }
        // ---- stage B for window 0 of this group ----
        {
            int c = tid;
#pragma unroll
            for (int rep = 0; rep < 2; ++rep, c += 512) {
                int n = c >> 2, q = c & 3;
                uint4 v = *(const uint4*)(wt + (size_t)n * K + fb + q * 8);
                *(uint4*)&ldsB[n * LDB + q * 8] = v;
            }
        }
        __syncthreads();

#pragma unroll
        for (int w = 0; w < 3; ++w) {
            // ---- fragments + MFMA for window w ----
            bf16x8 af[4], bfr[4];
#pragma unroll
            for (int mi = 0; mi < 4; ++mi) {
                int r = wm * 64 + mi * 16 + lrow + w;   // emb row (s = s0-1+r)
                af[mi] = *(const bf16x8*)&ldsA[r * LDA + lgrp * 8];
            }
#pragma unroll
            for (int ni = 0; ni < 4; ++ni) {
                if (wn * 64 + ni * 16 < FN) {
                    int n = wn * 64 + ni * 16 + lrow;
                    bfr[ni] = *(const bf16x8*)&ldsB[n * LDB + lgrp * 8];
                }
            }
#pragma unroll
            for (int mi = 0; mi < 4; ++mi)
#pragma unroll
                for (int ni = 0; ni < 4; ++ni)
                    if (wn * 64 + ni * 16 < FN)
                        acc[mi][ni] = __builtin_amdgcn_mfma_f32_16x16x32_bf16(
                            af[mi], bfr[ni], acc[mi][ni], 0, 0, 0);

            if (w < 2) {
                __syncthreads();   // B reads of window w done
                // ---- stage B for window w+1: k = (w+1)*FEAT + fb ----
                int c = tid;
#pragma unroll
                for (int rep = 0; rep < 2; ++rep, c += 512) {
                    int n = c >> 2, q = c & 3;
                    uint4 v = *(const uint4*)(wt + (size_t)n * K
                                              + (w + 1) * FEAT + fb + q * 8);
                    *(uint4*)&ldsB[n * LDB + q * 8] = v;
                }
                __syncthreads();
            }
        }
    }

    // ---- epilogue: bias + ReLU + segment max ----
    const int4 sb = *(const int4*)(segb + b * 4);
    float biasv[4];
#pragma unroll
    for (int ni = 0; ni < 4; ++ni) {
        int f = wn * 64 + ni * 16 + lrow;
        biasv[ni] = (f < FN) ? conv_b[f] : 0.0f;
    }
#pragma unroll
    for (int mi = 0; mi < 4; ++mi) {
#pragma unroll
        for (int r = 0; r < 4; ++r) {
            int s = s0 + wm * 64 + mi * 16 + lgrp * 4 + r;
            int mask = 0;
            if (s < sb.x) mask |= 1;
            if (s >= sb.y && s < sb.z) mask |= 2;
            if (s >= sb.w) mask |= 4;
            if (!mask) continue;
#pragma unroll
            for (int ni = 0; ni < 4; ++ni) {
                int f = wn * 64 + ni * 16 + lrow;
                if (f >= FN) continue;
                float v = fmaxf(acc[mi][ni][r] + biasv[ni], 0.0f);
                unsigned uv = __float_as_uint(v);
                if (mask & 1) atomicMax(&maxbuf[f], uv);
                if (mask & 2) atomicMax(&maxbuf[FNP + f], uv);
                if (mask & 4) atomicMax(&maxbuf[2 * FNP + f], uv);
            }
        }
    }
    __syncthreads();
    unsigned* pc = pcnn + (size_t)b * 3 * FNP;
    for (int i = tid; i < 3 * FNP; i += 512) {
        unsigned m = maxbuf[i];
        if (((i & (FNP - 1)) < FN) && m) atomicMax(pc + i, m);
    }
}

// ---------------------------------------------------------------------------
// Kernel C: finale — tanh, 3-way softmax attention, rel_emb GEMV, tag softmax
// ---------------------------------------------------------------------------
__global__ __launch_bounds__(256) void finale_kernel(
    const float* __restrict__ pcnn, const float* __restrict__ att_weight,
    const float* __restrict__ rel_emb, const float* __restrict__ rel_bias,
    float* __restrict__ out)
{
    const int b = blockIdx.x;
    const int tid = threadIdx.x;
    __shared__ float red[12];
    __shared__ float satt[FN];
    __shared__ float wtag[56];

    const float* pc = pcnn + (size_t)b * 3 * FNP;
    float p0 = 0.f, p1 = 0.f, p2 = 0.f, aw = 0.f;
    if (tid < FN) {
        p0 = pc[tid];
        p1 = pc[FNP + tid];
        p2 = pc[2 * FNP + tid];
        aw = att_weight[b * FN + tid];
    }
    const int wid = tid >> 6;
#pragma unroll
    for (int t = 0; t < 3; ++t) {
        float pt = (t == 0) ? p0 : (t == 1) ? p1 : p2;
        float r = (tid < FN) ? aw * tanhf(pt) : 0.0f;
#pragma unroll
        for (int o = 32; o; o >>= 1) r += __shfl_xor(r, o);
        if ((tid & 63) == 0) red[t * 4 + wid] = r;
    }
    __syncthreads();
    float sc0 = red[0] + red[1] + red[2] + red[3];
    float sc1 = red[4] + red[5] + red[6] + red[7];
    float sc2 = red[8] + red[9] + red[10] + red[11];
    float m3s = fmaxf(sc0, fmaxf(sc1, sc2));
    float e0 = expf(sc0 - m3s), e1 = expf(sc1 - m3s), e2 = expf(sc2 - m3s);
    float inv = 1.0f / (e0 + e1 + e2);
    float a0 = e0 * inv, a1 = e1 * inv, a2 = e2 * inv;
    if (tid < FN) satt[tid] = tanhf(p0 * a0 + p1 * a1 + p2 * a2);
    __syncthreads();

    const int t = tid >> 2;
    const int part = tid & 3;
    if (t < TAG) {
        float s = 0.0f;
        for (int f = part; f < FN; f += 4) s += rel_emb[t * FN + f] * satt[f];
        s += __shfl_xor(s, 1);
        s += __shfl_xor(s, 2);
        if (part == 0) wtag[t] = s + rel_bias[b * TAG + t];
    }
    __syncthreads();

    if (tid < 64) {
        float v = (tid < TAG) ? wtag[tid] : -1e30f;
        float mx = v;
#pragma unroll
        for (int o = 32; o; o >>= 1) mx = fmaxf(mx, __shfl_xor(mx, o));
        float e = (tid < TAG) ? expf(v - mx) : 0.0f;
        float sum = e;
#pragma unroll
        for (int o = 32; o; o >>= 1) sum += __shfl_xor(sum, o);
        if (tid < TAG) out[b * TAG + tid] = e / sum;
    }
}

// ---------------------------------------------------------------------------
extern "C" void kernel_launch(void* const* d_in, const int* in_sizes, int n_in,
                              void* d_out, int out_size, void* d_ws, size_t ws_size,
                              hipStream_t stream)
{
    const int*   sentence  = (const int*)d_in[0];
    const int*   pos1      = (const int*)d_in[1];
    const int*   pos2      = (const int*)d_in[2];
    const float* word_emb  = (const float*)d_in[3];
    const float* pos1_emb  = (const float*)d_in[4];
    const float* pos2_emb  = (const float*)d_in[5];
    const float* rel_emb   = (const float*)d_in[6];
    const float* conv_w    = (const float*)d_in[7];
    const float* conv_b    = (const float*)d_in[8];
    const float* att_w     = (const float*)d_in[9];
    const float* rel_bias  = (const float*)d_in[10];
    float* out = (float*)d_out;

    // workspace layout
    int*            segb = (int*)d_ws;                                    //   4096 B
    unsigned*       pcnn = (unsigned*)((char*)d_ws + 4096);               // 786432 B
    unsigned short* wt   = (unsigned short*)((char*)d_ws + 4096 + 786432);// 491520 B

    wt_prep_kernel<<<dim3(K / 32, FNP / 32), 256, 0, stream>>>(conv_w, wt);
    bounds_kernel<<<B, 256, 0, stream>>>(pos1, pos2, segb, pcnn);
    conv_mfma_kernel<<<dim3(S / BM, B), 512, 0, stream>>>(
        sentence, pos1, pos2, word_emb, pos1_emb, pos2_emb,
        wt, conv_b, segb, pcnn);
    finale_kernel<<<B, 256, 0, stream>>>(
        (const float*)pcnn, att_w, rel_emb, rel_bias, out);
}